// Round 2
// baseline (370.365 us; speedup 1.0000x reference)
//
#include <hip/hip_runtime.h>

#define N_NODES 100000
#define SCAN_NB 128
#define SCAN_TPB 256

typedef _Float16 half_t;
typedef __attribute__((ext_vector_type(8))) _Float16 v8h;
typedef __attribute__((ext_vector_type(4))) _Float16 v4h;
typedef __attribute__((ext_vector_type(4))) float v4f;

// ---------------- prep1: degree count + weight transpose/convert ----------------

__global__ void prep1(const int* __restrict__ src, const int* __restrict__ dst,
                      int* __restrict__ ocnt, int* __restrict__ icnt, int E,
                      const float* __restrict__ W1, const float* __restrict__ W2,
                      const float* __restrict__ W3, half_t* __restrict__ Wt1,
                      half_t* __restrict__ Wt2, half_t* __restrict__ Wt3) {
    int t = blockIdx.x * blockDim.x + threadIdx.x;
    if (t < E) {
        atomicAdd(&ocnt[src[t]], 1);
        atomicAdd(&icnt[dst[t]], 1);
    } else {
        int u = t - E;
        if (u < 32768) {                      // W1: K=128, N=256
            int n = u >> 7, k = u & 127;
            Wt1[u] = (half_t)W1[(size_t)k * 256 + n];
        } else if (u < 65536) {               // W2: K=256, N=128
            int w = u - 32768;
            int n = w >> 8, k = w & 255;
            Wt2[w] = (half_t)W2[(size_t)k * 128 + n];
        } else if (u < 70656) {               // W3: K=128, N=40
            int w = u - 65536;
            int n = w >> 7, k = w & 127;
            Wt3[w] = (half_t)W3[(size_t)k * 40 + n];
        }
    }
}

// ---------------- scan (3-phase hierarchical) ----------------

__global__ __launch_bounds__(SCAN_TPB) void scan_reduce(const int* __restrict__ cnt,
                                                        int* __restrict__ blockSum, int n) {
    __shared__ int s[SCAN_TPB];
    int chunk = (n + SCAN_NB - 1) / SCAN_NB;
    int beg = blockIdx.x * chunk;
    int end = min(beg + chunk, n);
    int sum = 0;
    for (int i = beg + threadIdx.x; i < end; i += SCAN_TPB) sum += cnt[i];
    s[threadIdx.x] = sum;
    __syncthreads();
    for (int off = SCAN_TPB / 2; off > 0; off >>= 1) {
        if (threadIdx.x < off) s[threadIdx.x] += s[threadIdx.x + off];
        __syncthreads();
    }
    if (threadIdx.x == 0) blockSum[blockIdx.x] = s[0];
}

__global__ __launch_bounds__(SCAN_NB) void scan_offsets(int* __restrict__ blockSum,
                                                        int* __restrict__ rowptr_total) {
    __shared__ int s[SCAN_NB];
    int tid = threadIdx.x;
    int v = blockSum[tid];
    s[tid] = v;
    __syncthreads();
    for (int off = 1; off < SCAN_NB; off <<= 1) {
        int t = (tid >= off) ? s[tid - off] : 0;
        __syncthreads();
        s[tid] += t;
        __syncthreads();
    }
    blockSum[tid] = s[tid] - v;
    if (tid == SCAN_NB - 1) rowptr_total[0] = s[tid];
}

// Phase 3: in-chunk scan + block offset -> rowptr, cursor; also converts
// ocnt/icnt (int degree) -> inv-sqrt norms (float, in place).
__global__ __launch_bounds__(SCAN_TPB) void scan_final(int* __restrict__ cnt,
                                                       int* __restrict__ ocnt,
                                                       const int* __restrict__ blockSum,
                                                       int* __restrict__ rowptr,
                                                       int* __restrict__ cursor, int n) {
    __shared__ int s[SCAN_TPB];
    int chunk = (n + SCAN_NB - 1) / SCAN_NB;
    int beg = blockIdx.x * chunk;
    int end = min(beg + chunk, n);
    int carry = blockSum[blockIdx.x];
    for (int base = beg; base < end; base += SCAN_TPB) {
        int i = base + threadIdx.x;
        int v = (i < end) ? cnt[i] : 0;
        s[threadIdx.x] = v;
        __syncthreads();
        for (int off = 1; off < SCAN_TPB; off <<= 1) {
            int t = (threadIdx.x >= off) ? s[threadIdx.x - off] : 0;
            __syncthreads();
            s[threadIdx.x] += t;
            __syncthreads();
        }
        int excl = s[threadIdx.x] - v;
        if (i < end) {
            rowptr[i] = carry + excl;
            cursor[i] = carry + excl;
            int o = ocnt[i];
            ((float*)ocnt)[i] = rsqrtf((float)max(o, 1));
            ((float*)cnt)[i] = rsqrtf((float)max(v, 1));
        }
        int roundSum = s[SCAN_TPB - 1];
        __syncthreads();
        carry += roundSum;
    }
}

// ---------------- prep2: CSR fill + x convert (x * inv_out -> fp16) ----------------

__global__ void prep2(const int* __restrict__ src, const int* __restrict__ dst,
                      int* __restrict__ cursor, int* __restrict__ eidx, int E,
                      const float* __restrict__ x, const float* __restrict__ invOut,
                      half_t* __restrict__ xh) {
    int t = blockIdx.x * blockDim.x + threadIdx.x;
    if (t < E) {
        int pos = atomicAdd(&cursor[dst[t]], 1);
        eidx[pos] = src[t];
    } else {
        int u = t - E;
        if (u < N_NODES * 32) {
            int n = u >> 5;
            float4 v = ((const float4*)x)[u];
            float s = invOut[n];
            v4h h;
            h[0] = (half_t)(v.x * s);
            h[1] = (half_t)(v.y * s);
            h[2] = (half_t)(v.z * s);
            h[3] = (half_t)(v.w * s);
            *(v4h*)(xh + (size_t)u * 4) = h;
        }
    }
}

// ---------------- software-pipelined CSR row segment-sum into fp32 acc[8] -------
// R11: next batch's edge indices are issued WHILE the current batch's 4 dwordx4
// are in flight (counted vmcnt; idx latency hidden under accumulate).
// R12: avg degree is only 8 (~2 batches/row) so in-loop pipelining is nearly
// exhausted — remaining stall is cross-chain concurrency (see fused_l12).

template <int F>
__device__ __forceinline__ void gather_row(const half_t* __restrict__ x,
                                           const int* __restrict__ eidx,
                                           int beg, int end, int c, float* acc) {
    const half_t* __restrict__ xc = x + (size_t)c * 8;
    int n = end - beg;
    int nb = n & ~3;
    int j = 0;
    if (nb) {
        int i0 = eidx[beg + 0], i1 = eidx[beg + 1], i2 = eidx[beg + 2], i3 = eidx[beg + 3];
        do {
            v8h v0 = *(const v8h*)(xc + (size_t)i0 * F);
            v8h v1 = *(const v8h*)(xc + (size_t)i1 * F);
            v8h v2 = *(const v8h*)(xc + (size_t)i2 * F);
            v8h v3 = *(const v8h*)(xc + (size_t)i3 * F);
            j += 4;
            if (j < nb) {                      // prefetch next batch's indices
                i0 = eidx[beg + j + 0];        // (independent of v0..v3 -> stays
                i1 = eidx[beg + j + 1];        //  in flight across the data wait)
                i2 = eidx[beg + j + 2];
                i3 = eidx[beg + j + 3];
            }
#pragma unroll
            for (int q = 0; q < 8; ++q)
                acc[q] += ((float)v0[q] + (float)v1[q]) + ((float)v2[q] + (float)v3[q]);
        } while (j < nb);
    }
    for (; j < n; ++j) {
        int s = eidx[beg + j];
        v8h val = *(const v8h*)(xc + (size_t)s * F);
#pragma unroll
        for (int q = 0; q < 8; ++q) acc[q] += (float)val[q];
    }
}

// ---------------- fused gather + GEMM1 + GEMM2 (layers 1+2 transform) ----------
// R12: tile 64->32 rows. LDS 51.7KB -> 25.9KB so residency goes 3 -> 4 blocks/CU
// (wave-capped at 32 waves/CU, was 24: +33% concurrent latency chains), and each
// thread owns exactly ONE gather task (was 2 serial) -> per-wave gather chain
// halves. Barrier skew (slowest Poisson-tail row) taken over 512 tasks not 1024.
// 8 waves: 32 GEMM1 cols + 16 GEMM2 cols per wave, 2 m-tiles each.

__global__ __launch_bounds__(512) void fused_l12(
    const half_t* __restrict__ xh, const int* __restrict__ rowptr,
    const int* __restrict__ eidx, const half_t* __restrict__ Wt1,
    const half_t* __restrict__ Wt2,
    const float* __restrict__ invIn, const float* __restrict__ invOut,
    const float* __restrict__ b1, half_t* __restrict__ t2) {
    constexpr int K1 = 128, K2 = 256, N2 = 128;
    constexpr int ROWS = 32;
    constexpr int LDA = K1 + 8;
    constexpr int LDH = K2 + 8;
    __shared__ half_t As[ROWS][LDA];
    __shared__ half_t h1S[ROWS][LDH];
    __shared__ float iiS[ROWS], ioS[ROWS];
    const int tid = threadIdx.x;
    const int wave = tid >> 6, lane = tid & 63;
    const int quad = lane >> 4, l16 = lane & 15;
    const int m0 = blockIdx.x * ROWS;
    const int n0 = wave * 32;   // GEMM1 column span per wave (8 waves x 32 = 256)

    // B1 fragments into registers (overlap with gather)
    v8h b[2][4];
    float bv[2];
#pragma unroll
    for (int j = 0; j < 2; ++j) {
        int gn = n0 + j * 16 + l16;
        bv[j] = b1[gn];
#pragma unroll
        for (int kc = 0; kc < 4; ++kc)
            b[j][kc] = *(const v8h*)(Wt1 + (size_t)gn * K1 + kc * 32 + quad * 8);
    }
    if (tid < ROWS) {
        int gm = m0 + tid;
        bool ok = gm < N_NODES;
        iiS[tid] = ok ? invIn[gm] : 0.f;
        ioS[tid] = ok ? invOut[gm] : 0.f;
    }

    // gather phase: 32 rows x 16 chunks = 512 tasks, exactly 1 per thread
    {
        int r = tid >> 4, c = tid & 15;
        int gm = m0 + r;
        float acc[8] = {};
        if (gm < N_NODES)
            gather_row<K1>(xh, eidx, rowptr[gm], rowptr[gm + 1], c, acc);
        v8h o;
#pragma unroll
        for (int q = 0; q < 8; ++q) o[q] = (half_t)acc[q];
        *(v8h*)&As[r][c * 8] = o;
    }
    __syncthreads();

    // GEMM1 -> h1S (LDS): 2 m-tiles x 2 n-tiles per wave
    for (int mt = 0; mt < 2; ++mt) {
        v8h a[4];
#pragma unroll
        for (int kc = 0; kc < 4; ++kc)
            a[kc] = *(const v8h*)&As[mt * 16 + l16][kc * 32 + quad * 8];
        v4f acc[2] = {};
#pragma unroll
        for (int kc = 0; kc < 4; ++kc)
#pragma unroll
            for (int j = 0; j < 2; ++j)
                acc[j] = __builtin_amdgcn_mfma_f32_16x16x32_f16(a[kc], b[j][kc], acc[j], 0, 0, 0);
#pragma unroll
        for (int j = 0; j < 2; ++j) {
            int cn = n0 + j * 16 + l16;
#pragma unroll
            for (int r = 0; r < 4; ++r) {
                int lr = mt * 16 + quad * 4 + r;
                float z = (acc[j][r] * iiS[lr] + bv[j]) * ioS[lr];
                h1S[lr][cn] = (half_t)fmaxf(z, 0.f);
            }
        }
    }

    // B2 fragments: 1 n-tile per wave (8 x 16 = 128 cols)
    v8h b2[8];
    const int n02 = wave * 16;
    {
        int gn = n02 + l16;
#pragma unroll
        for (int kc = 0; kc < 8; ++kc)
            b2[kc] = *(const v8h*)(Wt2 + (size_t)gn * K2 + kc * 32 + quad * 8);
    }
    __syncthreads();

    // GEMM2: t2 = h1S @ W2
    for (int mt = 0; mt < 2; ++mt) {
        v8h a2[8];
#pragma unroll
        for (int kc = 0; kc < 8; ++kc)
            a2[kc] = *(const v8h*)&h1S[mt * 16 + l16][kc * 32 + quad * 8];
        v4f acc2 = {};
#pragma unroll
        for (int kc = 0; kc < 8; ++kc)
            acc2 = __builtin_amdgcn_mfma_f32_16x16x32_f16(a2[kc], b2[kc], acc2, 0, 0, 0);
        int gn = n02 + l16;
#pragma unroll
        for (int r = 0; r < 4; ++r) {
            int gm = m0 + mt * 16 + quad * 4 + r;
            if (gm < N_NODES) t2[(size_t)gm * N2 + gn] = (half_t)acc2[r];
        }
    }
}

// ---------------- fused gather(+relu epi) + GEMM, layer 3 ----------------
// 256 threads (R10 A/B: the 512-thr variant offset fused_l12's gain; R9 config
// restored — 4 gather tasks/thread, all 4 waves run the MFMA). LDS 17.7KB ->
// already 8-block (32-wave) capable at VGPR<=64.

__global__ __launch_bounds__(256) void fused_l3(
    const half_t* __restrict__ t2, const int* __restrict__ rowptr,
    const int* __restrict__ eidx, const half_t* __restrict__ Wt3,
    const float* __restrict__ invIn, const float* __restrict__ invOut,
    const float* __restrict__ b2, half_t* __restrict__ t3) {
    constexpr int K = 128, N = 40, LDA = K + 8;
    __shared__ half_t As[64][LDA];
    const int tid = threadIdx.x;
    const int wave = tid >> 6, lane = tid & 63;
    const int quad = lane >> 4, l16 = lane & 15;
    const int m0 = blockIdx.x * 64;

    v8h b[3][4];
#pragma unroll
    for (int j = 0; j < 3; ++j) {
        int gn = j * 16 + l16;
#pragma unroll
        for (int kc = 0; kc < 4; ++kc)
            b[j][kc] = (gn < N) ? *(const v8h*)(Wt3 + (size_t)gn * K + kc * 32 + quad * 8)
                                : (v8h)(half_t)0;
    }

#pragma unroll
    for (int t = 0; t < 4; ++t) {
        int task = tid + t * 256;
        int r = task >> 4, c = task & 15;
        int gm = m0 + r;
        float acc[8] = {};
        float ii = 0.f, io = 0.f;
        if (gm < N_NODES) {
            ii = invIn[gm];
            io = invOut[gm];
            gather_row<K>(t2, eidx, rowptr[gm], rowptr[gm + 1], c, acc);
        }
        v8h o;
#pragma unroll
        for (int q = 0; q < 8; ++q)
            o[q] = (half_t)fmaxf((acc[q] * ii + b2[c * 8 + q]) * io, 0.f);
        *(v8h*)&As[r][c * 8] = o;
    }
    __syncthreads();

    {
        int mt = wave;
        v8h a[4];
#pragma unroll
        for (int kc = 0; kc < 4; ++kc)
            a[kc] = *(const v8h*)&As[mt * 16 + l16][kc * 32 + quad * 8];
        v4f acc[3] = {};
#pragma unroll
        for (int kc = 0; kc < 4; ++kc)
#pragma unroll
            for (int j = 0; j < 3; ++j)
                acc[j] = __builtin_amdgcn_mfma_f32_16x16x32_f16(a[kc], b[j][kc], acc[j], 0, 0, 0);
#pragma unroll
        for (int j = 0; j < 3; ++j) {
            int gn = j * 16 + l16;
            if (gn >= N) continue;
#pragma unroll
            for (int r = 0; r < 4; ++r) {
                int gm = m0 + mt * 16 + quad * 4 + r;
                if (gm < N_NODES) t3[(size_t)gm * N + gn] = (half_t)acc[j][r];
            }
        }
    }
}

// ---------------- final gather (fp16 rows, fp32 out) ----------------

__global__ void gather_final(const half_t* __restrict__ x,
                             const int* __restrict__ rowptr, const int* __restrict__ eidx,
                             float* __restrict__ out, const float* __restrict__ invIn,
                             const float* __restrict__ bias) {
    constexpr int F = 40, V = 5;
    int t = blockIdx.x * blockDim.x + threadIdx.x;
    int n = t / V;
    int v = t - n * V;
    if (n >= N_NODES) return;
    float acc[8] = {};
    gather_row<F>(x, eidx, rowptr[n], rowptr[n + 1], v, acc);
    float ii = invIn[n];
    float* o = out + (size_t)n * F + v * 8;
#pragma unroll
    for (int q = 0; q < 8; ++q) o[q] = acc[q] * ii + bias[v * 8 + q];
}

// ---------------- launch ----------------

extern "C" void kernel_launch(void* const* d_in, const int* in_sizes, int n_in,
                              void* d_out, int out_size, void* d_ws, size_t ws_size,
                              hipStream_t stream) {
    const float* x  = (const float*)d_in[0];
    const int* src  = (const int*)d_in[1];
    const int* dst  = (const int*)d_in[2];
    const float* W1 = (const float*)d_in[3];
    const float* b1 = (const float*)d_in[4];
    const float* W2 = (const float*)d_in[5];
    const float* b2 = (const float*)d_in[6];
    const float* W3 = (const float*)d_in[7];
    const float* b3 = (const float*)d_in[8];
    float* out = (float*)d_out;
    const int E = in_sizes[1];

    char* ws = (char*)d_ws;
    int* ocnt     = (int*)ws;                     // 100000 (becomes inv_out f32)
    int* icnt     = (int*)(ws + 400000);          // 100000 (becomes inv_in f32)
    int* rowptr   = (int*)(ws + 800000);          // 100001
    int* cursor   = (int*)(ws + 1200256);         // 100000
    int* eidx     = (int*)(ws + 1600256);         // 800000 (3.2 MB)
    int* blockSum = (int*)(ws + 4800256);         // 128
    half_t* Wt1   = (half_t*)(ws + 4800768);      // 256x128 fp16 (64 KB)
    half_t* Wt2   = (half_t*)(ws + 4866304);      // 128x256 fp16 (64 KB)
    half_t* Wt3   = (half_t*)(ws + 4931840);      // 40x128 fp16 (10 KB)
    half_t* buf0  = (half_t*)(ws + 5000192);      // 25.6 MB: xh, later t3
    half_t* buf1  = (half_t*)(ws + 30600192);     // 25.6 MB: t2
    const float* inv_out = (const float*)ocnt;
    const float* inv_in  = (const float*)icnt;

    // ---- CSR + norms + weight conversion ----
    hipMemsetAsync(ocnt, 0, 800000, stream);
    prep1<<<(E + 70656 + 255) / 256, 256, 0, stream>>>(src, dst, ocnt, icnt, E,
                                                       W1, W2, W3, Wt1, Wt2, Wt3);
    scan_reduce<<<SCAN_NB, SCAN_TPB, 0, stream>>>(icnt, blockSum, N_NODES);
    scan_offsets<<<1, SCAN_NB, 0, stream>>>(blockSum, rowptr + N_NODES);
    scan_final<<<SCAN_NB, SCAN_TPB, 0, stream>>>(icnt, ocnt, blockSum, rowptr, cursor, N_NODES);
    prep2<<<(E + N_NODES * 32 + 255) / 256, 256, 0, stream>>>(src, dst, cursor, eidx, E,
                                                              x, inv_out, buf0);

    const int NB12 = (N_NODES + 31) / 32;  // 3125 (32-row tiles)
    const int NB   = (N_NODES + 63) / 64;  // 1563 (64-row tiles)

    // Layers 1+2: t2 = (relu((segsum(xh)@W1)*inv_in + b1)*inv_out) @ W2
    fused_l12<<<NB12, 512, 0, stream>>>(buf0, rowptr, eidx, Wt1, Wt2,
                                        inv_in, inv_out, b1, buf1);
    // Layer 3: t3 = (relu((segsum(t2))*inv_in + b2)*inv_out) @ W3
    fused_l3<<<NB, 256, 0, stream>>>(buf1, rowptr, eidx, Wt3, inv_in, inv_out, b2, buf0);
    // Final gather: out = segsum(t3)*inv_in + b3
    gather_final<<<(N_NODES * 5 + 255) / 256, 256, 0, stream>>>(
        buf0, rowptr, eidx, out, inv_in, b3);
}

// Round 3
// 368.495 us; speedup vs baseline: 1.0051x; 1.0051x over previous
//
#include <hip/hip_runtime.h>

#define N_NODES 100000
#define SCAN_NB 128
#define SCAN_TPB 256

typedef _Float16 half_t;
typedef __attribute__((ext_vector_type(8))) _Float16 v8h;
typedef __attribute__((ext_vector_type(4))) _Float16 v4h;
typedef __attribute__((ext_vector_type(4))) float v4f;

// ---------------- prep1: degree count + weight transpose/convert ----------------

__global__ void prep1(const int* __restrict__ src, const int* __restrict__ dst,
                      int* __restrict__ ocnt, int* __restrict__ icnt, int E,
                      const float* __restrict__ W1, const float* __restrict__ W2,
                      const float* __restrict__ W3, half_t* __restrict__ Wt1,
                      half_t* __restrict__ Wt2, half_t* __restrict__ Wt3) {
    int t = blockIdx.x * blockDim.x + threadIdx.x;
    if (t < E) {
        atomicAdd(&ocnt[src[t]], 1);
        atomicAdd(&icnt[dst[t]], 1);
    } else {
        int u = t - E;
        if (u < 32768) {                      // W1: K=128, N=256
            int n = u >> 7, k = u & 127;
            Wt1[u] = (half_t)W1[(size_t)k * 256 + n];
        } else if (u < 65536) {               // W2: K=256, N=128
            int w = u - 32768;
            int n = w >> 8, k = w & 255;
            Wt2[w] = (half_t)W2[(size_t)k * 128 + n];
        } else if (u < 70656) {               // W3: K=128, N=40
            int w = u - 65536;
            int n = w >> 7, k = w & 127;
            Wt3[w] = (half_t)W3[(size_t)k * 40 + n];
        }
    }
}

// ---------------- scan (3-phase hierarchical) ----------------

__global__ __launch_bounds__(SCAN_TPB) void scan_reduce(const int* __restrict__ cnt,
                                                        int* __restrict__ blockSum, int n) {
    __shared__ int s[SCAN_TPB];
    int chunk = (n + SCAN_NB - 1) / SCAN_NB;
    int beg = blockIdx.x * chunk;
    int end = min(beg + chunk, n);
    int sum = 0;
    for (int i = beg + threadIdx.x; i < end; i += SCAN_TPB) sum += cnt[i];
    s[threadIdx.x] = sum;
    __syncthreads();
    for (int off = SCAN_TPB / 2; off > 0; off >>= 1) {
        if (threadIdx.x < off) s[threadIdx.x] += s[threadIdx.x + off];
        __syncthreads();
    }
    if (threadIdx.x == 0) blockSum[blockIdx.x] = s[0];
}

__global__ __launch_bounds__(SCAN_NB) void scan_offsets(int* __restrict__ blockSum,
                                                        int* __restrict__ rowptr_total) {
    __shared__ int s[SCAN_NB];
    int tid = threadIdx.x;
    int v = blockSum[tid];
    s[tid] = v;
    __syncthreads();
    for (int off = 1; off < SCAN_NB; off <<= 1) {
        int t = (tid >= off) ? s[tid - off] : 0;
        __syncthreads();
        s[tid] += t;
        __syncthreads();
    }
    blockSum[tid] = s[tid] - v;
    if (tid == SCAN_NB - 1) rowptr_total[0] = s[tid];
}

// Phase 3: in-chunk scan + block offset -> rowptr, cursor; also converts
// ocnt/icnt (int degree) -> inv-sqrt norms (float, in place).
__global__ __launch_bounds__(SCAN_TPB) void scan_final(int* __restrict__ cnt,
                                                       int* __restrict__ ocnt,
                                                       const int* __restrict__ blockSum,
                                                       int* __restrict__ rowptr,
                                                       int* __restrict__ cursor, int n) {
    __shared__ int s[SCAN_TPB];
    int chunk = (n + SCAN_NB - 1) / SCAN_NB;
    int beg = blockIdx.x * chunk;
    int end = min(beg + chunk, n);
    int carry = blockSum[blockIdx.x];
    for (int base = beg; base < end; base += SCAN_TPB) {
        int i = base + threadIdx.x;
        int v = (i < end) ? cnt[i] : 0;
        s[threadIdx.x] = v;
        __syncthreads();
        for (int off = 1; off < SCAN_TPB; off <<= 1) {
            int t = (threadIdx.x >= off) ? s[threadIdx.x - off] : 0;
            __syncthreads();
            s[threadIdx.x] += t;
            __syncthreads();
        }
        int excl = s[threadIdx.x] - v;
        if (i < end) {
            rowptr[i] = carry + excl;
            cursor[i] = carry + excl;
            int o = ocnt[i];
            ((float*)ocnt)[i] = rsqrtf((float)max(o, 1));
            ((float*)cnt)[i] = rsqrtf((float)max(v, 1));
        }
        int roundSum = s[SCAN_TPB - 1];
        __syncthreads();
        carry += roundSum;
    }
}

// ---------------- prep2: CSR fill + x convert (x * inv_out -> fp16) ----------------

__global__ void prep2(const int* __restrict__ src, const int* __restrict__ dst,
                      int* __restrict__ cursor, int* __restrict__ eidx, int E,
                      const float* __restrict__ x, const float* __restrict__ invOut,
                      half_t* __restrict__ xh) {
    int t = blockIdx.x * blockDim.x + threadIdx.x;
    if (t < E) {
        int pos = atomicAdd(&cursor[dst[t]], 1);
        eidx[pos] = src[t];
    } else {
        int u = t - E;
        if (u < N_NODES * 32) {
            int n = u >> 5;
            float4 v = ((const float4*)x)[u];
            float s = invOut[n];
            v4h h;
            h[0] = (half_t)(v.x * s);
            h[1] = (half_t)(v.y * s);
            h[2] = (half_t)(v.z * s);
            h[3] = (half_t)(v.w * s);
            *(v4h*)(xh + (size_t)u * 4) = h;
        }
    }
}

// ---------------- CSR gather primitives ----------------
// R11: idx prefetch one batch ahead (counted vmcnt, idx latency under accum).
// R13: dual-row interleave — each thread runs TWO rows' chains fused, 8 data
// loads + 8 idx loads in flight (2x MLP at same occupancy; avg degree 8 means
// in-row pipelining alone is exhausted). VGPR growth is free: residency is
// LDS-capped (R8's 8-wide failure was occupancy-mediated, no longer applies).

template <int F>
__device__ __forceinline__ void gather_tail(const half_t* __restrict__ xc,
                                            const int* __restrict__ eidx,
                                            int beg, int end, float* acc) {
    int n = end - beg;
    int nb = n & ~3;
    int j = 0;
    if (nb) {
        int i0 = eidx[beg + 0], i1 = eidx[beg + 1], i2 = eidx[beg + 2], i3 = eidx[beg + 3];
        do {
            v8h v0 = *(const v8h*)(xc + (size_t)i0 * F);
            v8h v1 = *(const v8h*)(xc + (size_t)i1 * F);
            v8h v2 = *(const v8h*)(xc + (size_t)i2 * F);
            v8h v3 = *(const v8h*)(xc + (size_t)i3 * F);
            j += 4;
            if (j < nb) {
                i0 = eidx[beg + j + 0];
                i1 = eidx[beg + j + 1];
                i2 = eidx[beg + j + 2];
                i3 = eidx[beg + j + 3];
            }
#pragma unroll
            for (int q = 0; q < 8; ++q)
                acc[q] += ((float)v0[q] + (float)v1[q]) + ((float)v2[q] + (float)v3[q]);
        } while (j < nb);
    }
    for (; j < n; ++j) {
        int s = eidx[beg + j];
        v8h val = *(const v8h*)(xc + (size_t)s * F);
#pragma unroll
        for (int q = 0; q < 8; ++q) acc[q] += (float)val[q];
    }
}

template <int F>
__device__ __forceinline__ void gather_row(const half_t* __restrict__ x,
                                           const int* __restrict__ eidx,
                                           int beg, int end, int c, float* acc) {
    gather_tail<F>(x + (size_t)c * 8, eidx, beg, end, acc);
}

// Two rows, same column chunk, chains interleaved.
template <int F>
__device__ __forceinline__ void gather_row2(const half_t* __restrict__ x,
                                            const int* __restrict__ eidx,
                                            int beg0, int end0, int beg1, int end1,
                                            int c, float* acc0, float* acc1) {
    const half_t* __restrict__ xc = x + (size_t)c * 8;
    int nb0 = (end0 - beg0) & ~3;
    int nb1 = (end1 - beg1) & ~3;
    int j0 = 0, j1 = 0;
    if (nb0 && nb1) {
        int a0 = eidx[beg0 + 0], a1 = eidx[beg0 + 1], a2 = eidx[beg0 + 2], a3 = eidx[beg0 + 3];
        int c0 = eidx[beg1 + 0], c1 = eidx[beg1 + 1], c2 = eidx[beg1 + 2], c3 = eidx[beg1 + 3];
        while (true) {
            v8h u0 = *(const v8h*)(xc + (size_t)a0 * F);
            v8h u1 = *(const v8h*)(xc + (size_t)a1 * F);
            v8h u2 = *(const v8h*)(xc + (size_t)a2 * F);
            v8h u3 = *(const v8h*)(xc + (size_t)a3 * F);
            v8h w0 = *(const v8h*)(xc + (size_t)c0 * F);
            v8h w1 = *(const v8h*)(xc + (size_t)c1 * F);
            v8h w2 = *(const v8h*)(xc + (size_t)c2 * F);
            v8h w3 = *(const v8h*)(xc + (size_t)c3 * F);
            j0 += 4;
            j1 += 4;
            bool m0 = j0 < nb0, m1 = j1 < nb1;
            if (m0) {
                a0 = eidx[beg0 + j0 + 0];
                a1 = eidx[beg0 + j0 + 1];
                a2 = eidx[beg0 + j0 + 2];
                a3 = eidx[beg0 + j0 + 3];
            }
            if (m1) {
                c0 = eidx[beg1 + j1 + 0];
                c1 = eidx[beg1 + j1 + 1];
                c2 = eidx[beg1 + j1 + 2];
                c3 = eidx[beg1 + j1 + 3];
            }
#pragma unroll
            for (int q = 0; q < 8; ++q) {
                acc0[q] += ((float)u0[q] + (float)u1[q]) + ((float)u2[q] + (float)u3[q]);
                acc1[q] += ((float)w0[q] + (float)w1[q]) + ((float)w2[q] + (float)w3[q]);
            }
            if (!m0 || !m1) break;
        }
    }
    gather_tail<F>(xc, eidx, beg0 + j0, end0, acc0);
    gather_tail<F>(xc, eidx, beg1 + j1, end1, acc1);
}

// ---------------- fused gather + GEMM1 + GEMM2 (layers 1+2 transform) ----------
// 64-row tile (R12: 32-row regressed 70->87 — per-block fixed costs doubled,
// occupancy barely moved). 512 threads = 8 waves. Gather: 1024 tasks as 512
// dual-row fused chains (rows r, r+32, same chunk c). Per wave: 32 GEMM1 cols,
// 16 GEMM2 cols.

__global__ __launch_bounds__(512) void fused_l12(
    const half_t* __restrict__ xh, const int* __restrict__ rowptr,
    const int* __restrict__ eidx, const half_t* __restrict__ Wt1,
    const half_t* __restrict__ Wt2,
    const float* __restrict__ invIn, const float* __restrict__ invOut,
    const float* __restrict__ b1, half_t* __restrict__ t2) {
    constexpr int K1 = 128, K2 = 256, N2 = 128;
    constexpr int LDA = K1 + 8;
    constexpr int LDH = K2 + 8;
    __shared__ half_t As[64][LDA];
    __shared__ half_t h1S[64][LDH];
    __shared__ float iiS[64], ioS[64];
    const int tid = threadIdx.x;
    const int wave = tid >> 6, lane = tid & 63;
    const int quad = lane >> 4, l16 = lane & 15;
    const int m0 = blockIdx.x * 64;
    const int n0 = wave * 32;   // GEMM1 column span per wave (8 waves x 32 = 256)

    // B1 fragments into registers (overlap with gather)
    v8h b[2][4];
    float bv[2];
#pragma unroll
    for (int j = 0; j < 2; ++j) {
        int gn = n0 + j * 16 + l16;
        bv[j] = b1[gn];
#pragma unroll
        for (int kc = 0; kc < 4; ++kc)
            b[j][kc] = *(const v8h*)(Wt1 + (size_t)gn * K1 + kc * 32 + quad * 8);
    }
    if (tid < 64) {
        int gm = m0 + tid;
        bool ok = gm < N_NODES;
        iiS[tid] = ok ? invIn[gm] : 0.f;
        ioS[tid] = ok ? invOut[gm] : 0.f;
    }

    // gather phase: rows r and r+32, same chunk c, chains interleaved
    {
        int r = tid >> 4, c = tid & 15;
        int gm0 = m0 + r, gm1 = m0 + r + 32;
        int s0 = 0, e0 = 0, s1 = 0, e1 = 0;
        if (gm0 < N_NODES) { s0 = rowptr[gm0]; e0 = rowptr[gm0 + 1]; }
        if (gm1 < N_NODES) { s1 = rowptr[gm1]; e1 = rowptr[gm1 + 1]; }
        float acc0[8] = {}, acc1[8] = {};
        gather_row2<K1>(xh, eidx, s0, e0, s1, e1, c, acc0, acc1);
        v8h o0, o1;
#pragma unroll
        for (int q = 0; q < 8; ++q) { o0[q] = (half_t)acc0[q]; o1[q] = (half_t)acc1[q]; }
        *(v8h*)&As[r][c * 8] = o0;
        *(v8h*)&As[r + 32][c * 8] = o1;
    }
    __syncthreads();

    // GEMM1 -> h1S (LDS): 4 m-tiles x 2 n-tiles per wave
    for (int mt = 0; mt < 4; ++mt) {
        v8h a[4];
#pragma unroll
        for (int kc = 0; kc < 4; ++kc)
            a[kc] = *(const v8h*)&As[mt * 16 + l16][kc * 32 + quad * 8];
        v4f acc[2] = {};
#pragma unroll
        for (int kc = 0; kc < 4; ++kc)
#pragma unroll
            for (int j = 0; j < 2; ++j)
                acc[j] = __builtin_amdgcn_mfma_f32_16x16x32_f16(a[kc], b[j][kc], acc[j], 0, 0, 0);
#pragma unroll
        for (int j = 0; j < 2; ++j) {
            int cn = n0 + j * 16 + l16;
#pragma unroll
            for (int r = 0; r < 4; ++r) {
                int lr = mt * 16 + quad * 4 + r;
                float z = (acc[j][r] * iiS[lr] + bv[j]) * ioS[lr];
                h1S[lr][cn] = (half_t)fmaxf(z, 0.f);
            }
        }
    }

    // B2 fragments: 1 n-tile per wave (8 x 16 = 128 cols)
    v8h b2[8];
    const int n02 = wave * 16;
    {
        int gn = n02 + l16;
#pragma unroll
        for (int kc = 0; kc < 8; ++kc)
            b2[kc] = *(const v8h*)(Wt2 + (size_t)gn * K2 + kc * 32 + quad * 8);
    }
    __syncthreads();

    // GEMM2: t2 = h1S @ W2
    for (int mt = 0; mt < 4; ++mt) {
        v8h a2[8];
#pragma unroll
        for (int kc = 0; kc < 8; ++kc)
            a2[kc] = *(const v8h*)&h1S[mt * 16 + l16][kc * 32 + quad * 8];
        v4f acc2 = {};
#pragma unroll
        for (int kc = 0; kc < 8; ++kc)
            acc2 = __builtin_amdgcn_mfma_f32_16x16x32_f16(a2[kc], b2[kc], acc2, 0, 0, 0);
        int gn = n02 + l16;
#pragma unroll
        for (int r = 0; r < 4; ++r) {
            int gm = m0 + mt * 16 + quad * 4 + r;
            if (gm < N_NODES) t2[(size_t)gm * N2 + gn] = (half_t)acc2[r];
        }
    }
}

// ---------------- fused gather(+relu epi) + GEMM, layer 3 ----------------
// 256 threads; 4 gather tasks/thread run as 2 dual-row fused passes
// (rows r/r+16, then r+32/r+48 — same chunk c within each pass).

__global__ __launch_bounds__(256) void fused_l3(
    const half_t* __restrict__ t2, const int* __restrict__ rowptr,
    const int* __restrict__ eidx, const half_t* __restrict__ Wt3,
    const float* __restrict__ invIn, const float* __restrict__ invOut,
    const float* __restrict__ b2, half_t* __restrict__ t3) {
    constexpr int K = 128, N = 40, LDA = K + 8;
    __shared__ half_t As[64][LDA];
    const int tid = threadIdx.x;
    const int wave = tid >> 6, lane = tid & 63;
    const int quad = lane >> 4, l16 = lane & 15;
    const int m0 = blockIdx.x * 64;

    v8h b[3][4];
#pragma unroll
    for (int j = 0; j < 3; ++j) {
        int gn = j * 16 + l16;
#pragma unroll
        for (int kc = 0; kc < 4; ++kc)
            b[j][kc] = (gn < N) ? *(const v8h*)(Wt3 + (size_t)gn * K + kc * 32 + quad * 8)
                                : (v8h)(half_t)0;
    }

#pragma unroll
    for (int p = 0; p < 2; ++p) {
        int r0 = (tid >> 4) + p * 32, c = tid & 15;
        int r1 = r0 + 16;
        int gm0 = m0 + r0, gm1 = m0 + r1;
        int s0 = 0, e0 = 0, s1 = 0, e1 = 0;
        float ii0 = 0.f, io0 = 0.f, ii1 = 0.f, io1 = 0.f;
        if (gm0 < N_NODES) {
            s0 = rowptr[gm0]; e0 = rowptr[gm0 + 1];
            ii0 = invIn[gm0]; io0 = invOut[gm0];
        }
        if (gm1 < N_NODES) {
            s1 = rowptr[gm1]; e1 = rowptr[gm1 + 1];
            ii1 = invIn[gm1]; io1 = invOut[gm1];
        }
        float acc0[8] = {}, acc1[8] = {};
        gather_row2<K>(t2, eidx, s0, e0, s1, e1, c, acc0, acc1);
        v8h o0, o1;
#pragma unroll
        for (int q = 0; q < 8; ++q) {
            o0[q] = (half_t)fmaxf((acc0[q] * ii0 + b2[c * 8 + q]) * io0, 0.f);
            o1[q] = (half_t)fmaxf((acc1[q] * ii1 + b2[c * 8 + q]) * io1, 0.f);
        }
        *(v8h*)&As[r0][c * 8] = o0;
        *(v8h*)&As[r1][c * 8] = o1;
    }
    __syncthreads();

    {
        int mt = wave;
        v8h a[4];
#pragma unroll
        for (int kc = 0; kc < 4; ++kc)
            a[kc] = *(const v8h*)&As[mt * 16 + l16][kc * 32 + quad * 8];
        v4f acc[3] = {};
#pragma unroll
        for (int kc = 0; kc < 4; ++kc)
#pragma unroll
            for (int j = 0; j < 3; ++j)
                acc[j] = __builtin_amdgcn_mfma_f32_16x16x32_f16(a[kc], b[j][kc], acc[j], 0, 0, 0);
#pragma unroll
        for (int j = 0; j < 3; ++j) {
            int gn = j * 16 + l16;
            if (gn >= N) continue;
#pragma unroll
            for (int r = 0; r < 4; ++r) {
                int gm = m0 + mt * 16 + quad * 4 + r;
                if (gm < N_NODES) t3[(size_t)gm * N + gn] = (half_t)acc[j][r];
            }
        }
    }
}

// ---------------- final gather (fp16 rows, fp32 out) ----------------

__global__ void gather_final(const half_t* __restrict__ x,
                             const int* __restrict__ rowptr, const int* __restrict__ eidx,
                             float* __restrict__ out, const float* __restrict__ invIn,
                             const float* __restrict__ bias) {
    constexpr int F = 40, V = 5;
    int t = blockIdx.x * blockDim.x + threadIdx.x;
    int n = t / V;
    int v = t - n * V;
    if (n >= N_NODES) return;
    float acc[8] = {};
    gather_row<F>(x, eidx, rowptr[n], rowptr[n + 1], v, acc);
    float ii = invIn[n];
    float* o = out + (size_t)n * F + v * 8;
#pragma unroll
    for (int q = 0; q < 8; ++q) o[q] = acc[q] * ii + bias[v * 8 + q];
}

// ---------------- launch ----------------

extern "C" void kernel_launch(void* const* d_in, const int* in_sizes, int n_in,
                              void* d_out, int out_size, void* d_ws, size_t ws_size,
                              hipStream_t stream) {
    const float* x  = (const float*)d_in[0];
    const int* src  = (const int*)d_in[1];
    const int* dst  = (const int*)d_in[2];
    const float* W1 = (const float*)d_in[3];
    const float* b1 = (const float*)d_in[4];
    const float* W2 = (const float*)d_in[5];
    const float* b2 = (const float*)d_in[6];
    const float* W3 = (const float*)d_in[7];
    const float* b3 = (const float*)d_in[8];
    float* out = (float*)d_out;
    const int E = in_sizes[1];

    char* ws = (char*)d_ws;
    int* ocnt     = (int*)ws;                     // 100000 (becomes inv_out f32)
    int* icnt     = (int*)(ws + 400000);          // 100000 (becomes inv_in f32)
    int* rowptr   = (int*)(ws + 800000);          // 100001
    int* cursor   = (int*)(ws + 1200256);         // 100000
    int* eidx     = (int*)(ws + 1600256);         // 800000 (3.2 MB)
    int* blockSum = (int*)(ws + 4800256);         // 128
    half_t* Wt1   = (half_t*)(ws + 4800768);      // 256x128 fp16 (64 KB)
    half_t* Wt2   = (half_t*)(ws + 4866304);      // 128x256 fp16 (64 KB)
    half_t* Wt3   = (half_t*)(ws + 4931840);      // 40x128 fp16 (10 KB)
    half_t* buf0  = (half_t*)(ws + 5000192);      // 25.6 MB: xh, later t3
    half_t* buf1  = (half_t*)(ws + 30600192);     // 25.6 MB: t2
    const float* inv_out = (const float*)ocnt;
    const float* inv_in  = (const float*)icnt;

    // ---- CSR + norms + weight conversion ----
    hipMemsetAsync(ocnt, 0, 800000, stream);
    prep1<<<(E + 70656 + 255) / 256, 256, 0, stream>>>(src, dst, ocnt, icnt, E,
                                                       W1, W2, W3, Wt1, Wt2, Wt3);
    scan_reduce<<<SCAN_NB, SCAN_TPB, 0, stream>>>(icnt, blockSum, N_NODES);
    scan_offsets<<<1, SCAN_NB, 0, stream>>>(blockSum, rowptr + N_NODES);
    scan_final<<<SCAN_NB, SCAN_TPB, 0, stream>>>(icnt, ocnt, blockSum, rowptr, cursor, N_NODES);
    prep2<<<(E + N_NODES * 32 + 255) / 256, 256, 0, stream>>>(src, dst, cursor, eidx, E,
                                                              x, inv_out, buf0);

    const int NB = (N_NODES + 63) / 64;  // 1563

    // Layers 1+2: t2 = (relu((segsum(xh)@W1)*inv_in + b1)*inv_out) @ W2
    fused_l12<<<NB, 512, 0, stream>>>(buf0, rowptr, eidx, Wt1, Wt2,
                                      inv_in, inv_out, b1, buf1);
    // Layer 3: t3 = (relu((segsum(t2))*inv_in + b2)*inv_out) @ W3
    fused_l3<<<NB, 256, 0, stream>>>(buf1, rowptr, eidx, Wt3, inv_in, inv_out, b2, buf0);
    // Final gather: out = segsum(t3)*inv_in + b3
    gather_final<<<(N_NODES * 5 + 255) / 256, 256, 0, stream>>>(
        buf0, rowptr, eidx, out, inv_in, b3);
}

// Round 5
// 355.423 us; speedup vs baseline: 1.0420x; 1.0368x over previous
//
#include <hip/hip_runtime.h>

#define N_NODES 100000
#define SCAN_NB 128
#define SCAN_TPB 256

typedef _Float16 half_t;
typedef __attribute__((ext_vector_type(8))) _Float16 v8h;
typedef __attribute__((ext_vector_type(4))) _Float16 v4h;
typedef __attribute__((ext_vector_type(4))) float v4f;

// ---------------- prep1: degree count + weight transpose/convert ----------------

__global__ void prep1(const int* __restrict__ src, const int* __restrict__ dst,
                      int* __restrict__ ocnt, int* __restrict__ icnt, int E,
                      const float* __restrict__ W1, const float* __restrict__ W2,
                      const float* __restrict__ W3, half_t* __restrict__ Wt1,
                      half_t* __restrict__ Wt2, half_t* __restrict__ Wt3) {
    int t = blockIdx.x * blockDim.x + threadIdx.x;
    if (t < E) {
        atomicAdd(&ocnt[src[t]], 1);
        atomicAdd(&icnt[dst[t]], 1);
    } else {
        int u = t - E;
        if (u < 32768) {                      // W1: K=128, N=256
            int n = u >> 7, k = u & 127;
            Wt1[u] = (half_t)W1[(size_t)k * 256 + n];
        } else if (u < 65536) {               // W2: K=256, N=128
            int w = u - 32768;
            int n = w >> 8, k = w & 255;
            Wt2[w] = (half_t)W2[(size_t)k * 128 + n];
        } else if (u < 70656) {               // W3: K=128, N=40
            int w = u - 65536;
            int n = w >> 7, k = w & 127;
            Wt3[w] = (half_t)W3[(size_t)k * 40 + n];
        }
    }
}

// ---------------- scan (3-phase hierarchical) ----------------

__global__ __launch_bounds__(SCAN_TPB) void scan_reduce(const int* __restrict__ cnt,
                                                        int* __restrict__ blockSum, int n) {
    __shared__ int s[SCAN_TPB];
    int chunk = (n + SCAN_NB - 1) / SCAN_NB;
    int beg = blockIdx.x * chunk;
    int end = min(beg + chunk, n);
    int sum = 0;
    for (int i = beg + threadIdx.x; i < end; i += SCAN_TPB) sum += cnt[i];
    s[threadIdx.x] = sum;
    __syncthreads();
    for (int off = SCAN_TPB / 2; off > 0; off >>= 1) {
        if (threadIdx.x < off) s[threadIdx.x] += s[threadIdx.x + off];
        __syncthreads();
    }
    if (threadIdx.x == 0) blockSum[blockIdx.x] = s[0];
}

__global__ __launch_bounds__(SCAN_NB) void scan_offsets(int* __restrict__ blockSum,
                                                        int* __restrict__ rowptr_total) {
    __shared__ int s[SCAN_NB];
    int tid = threadIdx.x;
    int v = blockSum[tid];
    s[tid] = v;
    __syncthreads();
    for (int off = 1; off < SCAN_NB; off <<= 1) {
        int t = (tid >= off) ? s[tid - off] : 0;
        __syncthreads();
        s[tid] += t;
        __syncthreads();
    }
    blockSum[tid] = s[tid] - v;
    if (tid == SCAN_NB - 1) rowptr_total[0] = s[tid];
}

// Phase 3: in-chunk scan + block offset -> rowptr, cursor; also converts
// ocnt/icnt (int degree) -> inv-sqrt norms (float, in place).
__global__ __launch_bounds__(SCAN_TPB) void scan_final(int* __restrict__ cnt,
                                                       int* __restrict__ ocnt,
                                                       const int* __restrict__ blockSum,
                                                       int* __restrict__ rowptr,
                                                       int* __restrict__ cursor, int n) {
    __shared__ int s[SCAN_TPB];
    int chunk = (n + SCAN_NB - 1) / SCAN_NB;
    int beg = blockIdx.x * chunk;
    int end = min(beg + chunk, n);
    int carry = blockSum[blockIdx.x];
    for (int base = beg; base < end; base += SCAN_TPB) {
        int i = base + threadIdx.x;
        int v = (i < end) ? cnt[i] : 0;
        s[threadIdx.x] = v;
        __syncthreads();
        for (int off = 1; off < SCAN_TPB; off <<= 1) {
            int t = (threadIdx.x >= off) ? s[threadIdx.x - off] : 0;
            __syncthreads();
            s[threadIdx.x] += t;
            __syncthreads();
        }
        int excl = s[threadIdx.x] - v;
        if (i < end) {
            rowptr[i] = carry + excl;
            cursor[i] = carry + excl;
            int o = ocnt[i];
            ((float*)ocnt)[i] = rsqrtf((float)max(o, 1));
            ((float*)cnt)[i] = rsqrtf((float)max(v, 1));
        }
        int roundSum = s[SCAN_TPB - 1];
        __syncthreads();
        carry += roundSum;
    }
}

// ---------------- prep2: CSR fill + x convert (x * inv_out -> fp16) ----------------

__global__ void prep2(const int* __restrict__ src, const int* __restrict__ dst,
                      int* __restrict__ cursor, int* __restrict__ eidx, int E,
                      const float* __restrict__ x, const float* __restrict__ invOut,
                      half_t* __restrict__ xh) {
    int t = blockIdx.x * blockDim.x + threadIdx.x;
    if (t < E) {
        int pos = atomicAdd(&cursor[dst[t]], 1);
        eidx[pos] = src[t];
    } else {
        int u = t - E;
        if (u < N_NODES * 32) {
            int n = u >> 5;
            float4 v = ((const float4*)x)[u];
            float s = invOut[n];
            v4h h;
            h[0] = (half_t)(v.x * s);
            h[1] = (half_t)(v.y * s);
            h[2] = (half_t)(v.z * s);
            h[3] = (half_t)(v.w * s);
            *(v4h*)(xh + (size_t)u * 4) = h;
        }
    }
}

// ---------------- CSR row segment-sum into fp32 acc[8] ----------------
// R11: idx prefetch one batch ahead (counted vmcnt, idx latency under accum).
// R13: dual-row interleave regressed (lockstep min(nb0,nb1) + tails) — single
// row per thread is the keeper. R14/R15: gather lives in barrier-free,
// LDS-free kernels at 32 waves/CU (see gather1/gather2).

template <int F>
__device__ __forceinline__ void gather_row(const half_t* __restrict__ x,
                                           const int* __restrict__ eidx,
                                           int beg, int end, int c, float* acc) {
    const half_t* __restrict__ xc = x + (size_t)c * 8;
    int n = end - beg;
    int nb = n & ~3;
    int j = 0;
    if (nb) {
        int i0 = eidx[beg + 0], i1 = eidx[beg + 1], i2 = eidx[beg + 2], i3 = eidx[beg + 3];
        do {
            v8h v0 = *(const v8h*)(xc + (size_t)i0 * F);
            v8h v1 = *(const v8h*)(xc + (size_t)i1 * F);
            v8h v2 = *(const v8h*)(xc + (size_t)i2 * F);
            v8h v3 = *(const v8h*)(xc + (size_t)i3 * F);
            j += 4;
            if (j < nb) {
                i0 = eidx[beg + j + 0];
                i1 = eidx[beg + j + 1];
                i2 = eidx[beg + j + 2];
                i3 = eidx[beg + j + 3];
            }
#pragma unroll
            for (int q = 0; q < 8; ++q)
                acc[q] += ((float)v0[q] + (float)v1[q]) + ((float)v2[q] + (float)v3[q]);
        } while (j < nb);
    }
    for (; j < n; ++j) {
        int s = eidx[beg + j];
        v8h val = *(const v8h*)(xc + (size_t)s * F);
#pragma unroll
        for (int q = 0; q < 8; ++q) acc[q] += (float)val[q];
    }
}

// ---------------- R14: standalone gather kernels (no LDS, no barriers) --------
// Fused gather+GEMM was ~70% stall with occupancy LDS-capped (avg ~11 waves/CU)
// and barrier skew = max-degree over 64 rows (~2.4x mean). Standalone: 32
// waves/CU (3x the latency chains), wave retires on its own 4 rows (skew
// max-of-4 ~ 1.45x), output is a coalesced global write.
// R15: two-buffer ping-pong (R4's third buffer overran the ~56MB workspace and
// crashed the container — footprint restored to the proven 56.2 MB).

__global__ __launch_bounds__(256, 8) void gather1(
    const half_t* __restrict__ xh, const int* __restrict__ rowptr,
    const int* __restrict__ eidx, half_t* __restrict__ A1) {
    int t = blockIdx.x * 256 + threadIdx.x;
    int n = t >> 4, c = t & 15;
    if (n >= N_NODES) return;
    float acc[8] = {};
    gather_row<128>(xh, eidx, rowptr[n], rowptr[n + 1], c, acc);
    v8h o;
#pragma unroll
    for (int q = 0; q < 8; ++q) o[q] = (half_t)acc[q];
    *(v8h*)(A1 + (size_t)n * 128 + c * 8) = o;
}

// gather2: segsum(t2) with fused layer-2 epilogue:
//   A2 = relu((g*invIn + b2)*invOut) in fp16 (pre-scaled for layer-3 agg).
__global__ __launch_bounds__(256, 8) void gather2(
    const half_t* __restrict__ t2, const int* __restrict__ rowptr,
    const int* __restrict__ eidx, const float* __restrict__ invIn,
    const float* __restrict__ invOut, const float* __restrict__ b2,
    half_t* __restrict__ A2) {
    int t = blockIdx.x * 256 + threadIdx.x;
    int n = t >> 4, c = t & 15;
    if (n >= N_NODES) return;
    float acc[8] = {};
    gather_row<128>(t2, eidx, rowptr[n], rowptr[n + 1], c, acc);
    float ii = invIn[n], io = invOut[n];
    float4 blo = ((const float4*)b2)[c * 2];
    float4 bhi = ((const float4*)b2)[c * 2 + 1];
    float bb[8] = {blo.x, blo.y, blo.z, blo.w, bhi.x, bhi.y, bhi.z, bhi.w};
    v8h o;
#pragma unroll
    for (int q = 0; q < 8; ++q)
        o[q] = (half_t)fmaxf((acc[q] * ii + bb[q]) * io, 0.f);
    *(v8h*)(A2 + (size_t)n * 128 + c * 8) = o;
}

// ---------------- R14: dense MLP kernels (uniform, MFMA-bound) ----------------
// mlp12: t2 = (relu((A1@W1)*invIn + b1)*invOut) @ W2. Same MFMA structure as
// the old fused_l12, but the A-tile comes from a coalesced global read.

__global__ __launch_bounds__(512) void mlp12(
    const half_t* __restrict__ A1, const half_t* __restrict__ Wt1,
    const half_t* __restrict__ Wt2,
    const float* __restrict__ invIn, const float* __restrict__ invOut,
    const float* __restrict__ b1, half_t* __restrict__ t2) {
    constexpr int K1 = 128, K2 = 256, N2 = 128;
    constexpr int LDA = K1 + 8;
    constexpr int LDH = K2 + 8;
    __shared__ half_t As[64][LDA];
    __shared__ half_t h1S[64][LDH];
    __shared__ float iiS[64], ioS[64];
    const int tid = threadIdx.x;
    const int wave = tid >> 6, lane = tid & 63;
    const int quad = lane >> 4, l16 = lane & 15;
    const int m0 = blockIdx.x * 64;
    const int n0 = wave * 32;   // GEMM1 column span per wave (8 waves x 32 = 256)

    // B1 fragments into registers (overlap with A-load)
    v8h b[2][4];
    float bv[2];
#pragma unroll
    for (int j = 0; j < 2; ++j) {
        int gn = n0 + j * 16 + l16;
        bv[j] = b1[gn];
#pragma unroll
        for (int kc = 0; kc < 4; ++kc)
            b[j][kc] = *(const v8h*)(Wt1 + (size_t)gn * K1 + kc * 32 + quad * 8);
    }
    if (tid < 64) {
        int gm = m0 + tid;
        bool ok = gm < N_NODES;
        iiS[tid] = ok ? invIn[gm] : 0.f;
        ioS[tid] = ok ? invOut[gm] : 0.f;
    }

    // A-tile load: 64 rows x 16 chunks = 1024 dwordx4, 2 per thread (coalesced)
#pragma unroll
    for (int p = 0; p < 2; ++p) {
        int task = tid + p * 512;
        int r = task >> 4, c = task & 15;
        int gm = m0 + r;
        v8h v = (gm < N_NODES) ? *(const v8h*)(A1 + (size_t)gm * K1 + c * 8)
                               : (v8h)(half_t)0;
        *(v8h*)&As[r][c * 8] = v;
    }
    __syncthreads();

    // GEMM1 -> h1S (LDS): 4 m-tiles x 2 n-tiles per wave
    for (int mt = 0; mt < 4; ++mt) {
        v8h a[4];
#pragma unroll
        for (int kc = 0; kc < 4; ++kc)
            a[kc] = *(const v8h*)&As[mt * 16 + l16][kc * 32 + quad * 8];
        v4f acc[2] = {};
#pragma unroll
        for (int kc = 0; kc < 4; ++kc)
#pragma unroll
            for (int j = 0; j < 2; ++j)
                acc[j] = __builtin_amdgcn_mfma_f32_16x16x32_f16(a[kc], b[j][kc], acc[j], 0, 0, 0);
#pragma unroll
        for (int j = 0; j < 2; ++j) {
            int cn = n0 + j * 16 + l16;
#pragma unroll
            for (int r = 0; r < 4; ++r) {
                int lr = mt * 16 + quad * 4 + r;
                float z = (acc[j][r] * iiS[lr] + bv[j]) * ioS[lr];
                h1S[lr][cn] = (half_t)fmaxf(z, 0.f);
            }
        }
    }

    // B2 fragments: 1 n-tile per wave (8 x 16 = 128 cols)
    v8h b2[8];
    const int n02 = wave * 16;
    {
        int gn = n02 + l16;
#pragma unroll
        for (int kc = 0; kc < 8; ++kc)
            b2[kc] = *(const v8h*)(Wt2 + (size_t)gn * K2 + kc * 32 + quad * 8);
    }
    __syncthreads();

    // GEMM2: t2 = h1S @ W2
    for (int mt = 0; mt < 4; ++mt) {
        v8h a2[8];
#pragma unroll
        for (int kc = 0; kc < 8; ++kc)
            a2[kc] = *(const v8h*)&h1S[mt * 16 + l16][kc * 32 + quad * 8];
        v4f acc2 = {};
#pragma unroll
        for (int kc = 0; kc < 8; ++kc)
            acc2 = __builtin_amdgcn_mfma_f32_16x16x32_f16(a2[kc], b2[kc], acc2, 0, 0, 0);
        int gn = n02 + l16;
#pragma unroll
        for (int r = 0; r < 4; ++r) {
            int gm = m0 + mt * 16 + quad * 4 + r;
            if (gm < N_NODES) t2[(size_t)gm * N2 + gn] = (half_t)acc2[r];
        }
    }
}

// mlp3: t3 = A2 @ W3 (A2 already relu'd + pre-scaled by gather2's epilogue).

__global__ __launch_bounds__(256) void mlp3(
    const half_t* __restrict__ A2, const half_t* __restrict__ Wt3,
    half_t* __restrict__ t3) {
    constexpr int K = 128, N = 40, LDA = K + 8;
    __shared__ half_t As[64][LDA];
    const int tid = threadIdx.x;
    const int wave = tid >> 6, lane = tid & 63;
    const int quad = lane >> 4, l16 = lane & 15;
    const int m0 = blockIdx.x * 64;

    v8h b[3][4];
#pragma unroll
    for (int j = 0; j < 3; ++j) {
        int gn = j * 16 + l16;
#pragma unroll
        for (int kc = 0; kc < 4; ++kc)
            b[j][kc] = (gn < N) ? *(const v8h*)(Wt3 + (size_t)gn * K + kc * 32 + quad * 8)
                                : (v8h)(half_t)0;
    }

#pragma unroll
    for (int p = 0; p < 4; ++p) {
        int task = tid + p * 256;
        int r = task >> 4, c = task & 15;
        int gm = m0 + r;
        v8h v = (gm < N_NODES) ? *(const v8h*)(A2 + (size_t)gm * K + c * 8)
                               : (v8h)(half_t)0;
        *(v8h*)&As[r][c * 8] = v;
    }
    __syncthreads();

    {
        int mt = wave;
        v8h a[4];
#pragma unroll
        for (int kc = 0; kc < 4; ++kc)
            a[kc] = *(const v8h*)&As[mt * 16 + l16][kc * 32 + quad * 8];
        v4f acc[3] = {};
#pragma unroll
        for (int kc = 0; kc < 4; ++kc)
#pragma unroll
            for (int j = 0; j < 3; ++j)
                acc[j] = __builtin_amdgcn_mfma_f32_16x16x32_f16(a[kc], b[j][kc], acc[j], 0, 0, 0);
#pragma unroll
        for (int j = 0; j < 3; ++j) {
            int gn = j * 16 + l16;
            if (gn >= N) continue;
#pragma unroll
            for (int r = 0; r < 4; ++r) {
                int gm = m0 + mt * 16 + quad * 4 + r;
                if (gm < N_NODES) t3[(size_t)gm * N + gn] = (half_t)acc[j][r];
            }
        }
    }
}

// ---------------- final gather (fp16 rows, fp32 out) ----------------

__global__ __launch_bounds__(256, 8) void gather_final(
    const half_t* __restrict__ x,
    const int* __restrict__ rowptr, const int* __restrict__ eidx,
    float* __restrict__ out, const float* __restrict__ invIn,
    const float* __restrict__ bias) {
    constexpr int F = 40, V = 5;
    int t = blockIdx.x * blockDim.x + threadIdx.x;
    int n = t / V;
    int v = t - n * V;
    if (n >= N_NODES) return;
    float acc[8] = {};
    gather_row<F>(x, eidx, rowptr[n], rowptr[n + 1], v, acc);
    float ii = invIn[n];
    float* o = out + (size_t)n * F + v * 8;
#pragma unroll
    for (int q = 0; q < 8; ++q) o[q] = acc[q] * ii + bias[v * 8 + q];
}

// ---------------- launch ----------------

extern "C" void kernel_launch(void* const* d_in, const int* in_sizes, int n_in,
                              void* d_out, int out_size, void* d_ws, size_t ws_size,
                              hipStream_t stream) {
    const float* x  = (const float*)d_in[0];
    const int* src  = (const int*)d_in[1];
    const int* dst  = (const int*)d_in[2];
    const float* W1 = (const float*)d_in[3];
    const float* b1 = (const float*)d_in[4];
    const float* W2 = (const float*)d_in[5];
    const float* b2 = (const float*)d_in[6];
    const float* W3 = (const float*)d_in[7];
    const float* b3 = (const float*)d_in[8];
    float* out = (float*)d_out;
    const int E = in_sizes[1];

    char* ws = (char*)d_ws;
    int* ocnt     = (int*)ws;                     // 100000 (becomes inv_out f32)
    int* icnt     = (int*)(ws + 400000);          // 100000 (becomes inv_in f32)
    int* rowptr   = (int*)(ws + 800000);          // 100001
    int* cursor   = (int*)(ws + 1200256);         // 100000
    int* eidx     = (int*)(ws + 1600256);         // 800000 (3.2 MB)
    int* blockSum = (int*)(ws + 4800256);         // 128
    half_t* Wt1   = (half_t*)(ws + 4800768);      // 256x128 fp16 (64 KB)
    half_t* Wt2   = (half_t*)(ws + 4866304);      // 128x256 fp16 (64 KB)
    half_t* Wt3   = (half_t*)(ws + 4931840);      // 40x128 fp16 (10 KB)
    half_t* bufA  = (half_t*)(ws + 5000192);      // 25.6 MB: xh -> t2 -> t3
    half_t* bufB  = (half_t*)(ws + 30600192);     // 25.6 MB: A1 -> A2  (56.2 MB total)
    const float* inv_out = (const float*)ocnt;
    const float* inv_in  = (const float*)icnt;

    // ---- CSR + norms + weight conversion ----
    hipMemsetAsync(ocnt, 0, 800000, stream);
    prep1<<<(E + 70656 + 255) / 256, 256, 0, stream>>>(src, dst, ocnt, icnt, E,
                                                       W1, W2, W3, Wt1, Wt2, Wt3);
    scan_reduce<<<SCAN_NB, SCAN_TPB, 0, stream>>>(icnt, blockSum, N_NODES);
    scan_offsets<<<1, SCAN_NB, 0, stream>>>(blockSum, rowptr + N_NODES);
    scan_final<<<SCAN_NB, SCAN_TPB, 0, stream>>>(icnt, ocnt, blockSum, rowptr, cursor, N_NODES);
    prep2<<<(E + N_NODES * 32 + 255) / 256, 256, 0, stream>>>(src, dst, cursor, eidx, E,
                                                              x, inv_out, bufA);

    const int NBG = (N_NODES * 16 + 255) / 256;  // 6250 (gather: 16 thr/row)
    const int NB  = (N_NODES + 63) / 64;         // 1563 (MLP: 64-row tiles)

    // Layer 1 aggregation: A1 = segsum(xh)          (reads bufA, writes bufB)
    gather1<<<NBG, 256, 0, stream>>>(bufA, rowptr, eidx, bufB);
    // Layers 1+2 transform: t2 = MLP(A1)            (reads bufB, writes bufA; xh dead)
    mlp12<<<NB, 512, 0, stream>>>(bufB, Wt1, Wt2, inv_in, inv_out, b1, bufA);
    // Layer 2 aggregation + epilogue: A2            (reads bufA, writes bufB; A1 dead)
    gather2<<<NBG, 256, 0, stream>>>(bufA, rowptr, eidx, inv_in, inv_out, b2, bufB);
    // Layer 3 transform: t3 = A2 @ W3               (reads bufB, writes bufA; t2 dead)
    mlp3<<<NB, 256, 0, stream>>>(bufB, Wt3, bufA);
    // Final aggregation: out = segsum(t3)*inv_in+b3 (reads bufA)
    gather_final<<<(N_NODES * 5 + 255) / 256, 256, 0, stream>>>(
        bufA, rowptr, eidx, out, inv_in, b3);
}

// Round 6
// 330.434 us; speedup vs baseline: 1.1208x; 1.0756x over previous
//
#include <hip/hip_runtime.h>

#define N_NODES 100000
#define SCAN_NB 128
#define SCAN_TPB 256

typedef _Float16 half_t;
typedef __attribute__((ext_vector_type(8))) _Float16 v8h;
typedef __attribute__((ext_vector_type(4))) _Float16 v4h;
typedef __attribute__((ext_vector_type(4))) float v4f;

// ---------------- prep1: degree count (+CSR local offset) + weight convert ----
// R16: icnt's atomicAdd RETURN VALUE is the within-bucket CSR position (loc).
// This removes prep2's 800K atomic-with-return cursor ops — per-edge atomic
// count drops 3 -> 2. prep1 measured pinned at ~25G atomics/s (64us, VALUBusy
// 0.35%): atomic transactions are the currency here, nothing else matters.

__global__ void prep1(const int* __restrict__ src, const int* __restrict__ dst,
                      int* __restrict__ ocnt, int* __restrict__ icnt,
                      int* __restrict__ loc, int E,
                      const float* __restrict__ W1, const float* __restrict__ W2,
                      const float* __restrict__ W3, half_t* __restrict__ Wt1,
                      half_t* __restrict__ Wt2, half_t* __restrict__ Wt3) {
    int t = blockIdx.x * blockDim.x + threadIdx.x;
    if (t < E) {
        loc[t] = atomicAdd(&icnt[dst[t]], 1);   // count AND position
        atomicAdd(&ocnt[src[t]], 1);
    } else {
        int u = t - E;
        if (u < 32768) {                      // W1: K=128, N=256
            int n = u >> 7, k = u & 127;
            Wt1[u] = (half_t)W1[(size_t)k * 256 + n];
        } else if (u < 65536) {               // W2: K=256, N=128
            int w = u - 32768;
            int n = w >> 8, k = w & 255;
            Wt2[w] = (half_t)W2[(size_t)k * 128 + n];
        } else if (u < 70656) {               // W3: K=128, N=40
            int w = u - 65536;
            int n = w >> 7, k = w & 127;
            Wt3[w] = (half_t)W3[(size_t)k * 40 + n];
        }
    }
}

// ---------------- scan (3-phase hierarchical) ----------------

__global__ __launch_bounds__(SCAN_TPB) void scan_reduce(const int* __restrict__ cnt,
                                                        int* __restrict__ blockSum, int n) {
    __shared__ int s[SCAN_TPB];
    int chunk = (n + SCAN_NB - 1) / SCAN_NB;
    int beg = blockIdx.x * chunk;
    int end = min(beg + chunk, n);
    int sum = 0;
    for (int i = beg + threadIdx.x; i < end; i += SCAN_TPB) sum += cnt[i];
    s[threadIdx.x] = sum;
    __syncthreads();
    for (int off = SCAN_TPB / 2; off > 0; off >>= 1) {
        if (threadIdx.x < off) s[threadIdx.x] += s[threadIdx.x + off];
        __syncthreads();
    }
    if (threadIdx.x == 0) blockSum[blockIdx.x] = s[0];
}

__global__ __launch_bounds__(SCAN_NB) void scan_offsets(int* __restrict__ blockSum,
                                                        int* __restrict__ rowptr_total) {
    __shared__ int s[SCAN_NB];
    int tid = threadIdx.x;
    int v = blockSum[tid];
    s[tid] = v;
    __syncthreads();
    for (int off = 1; off < SCAN_NB; off <<= 1) {
        int t = (tid >= off) ? s[tid - off] : 0;
        __syncthreads();
        s[tid] += t;
        __syncthreads();
    }
    blockSum[tid] = s[tid] - v;
    if (tid == SCAN_NB - 1) rowptr_total[0] = s[tid];
}

// Phase 3: in-chunk scan + block offset -> rowptr; converts ocnt/icnt (int
// degree) -> inv-sqrt norms (float, in place). (cursor removed in R16.)
__global__ __launch_bounds__(SCAN_TPB) void scan_final(int* __restrict__ cnt,
                                                       int* __restrict__ ocnt,
                                                       const int* __restrict__ blockSum,
                                                       int* __restrict__ rowptr, int n) {
    __shared__ int s[SCAN_TPB];
    int chunk = (n + SCAN_NB - 1) / SCAN_NB;
    int beg = blockIdx.x * chunk;
    int end = min(beg + chunk, n);
    int carry = blockSum[blockIdx.x];
    for (int base = beg; base < end; base += SCAN_TPB) {
        int i = base + threadIdx.x;
        int v = (i < end) ? cnt[i] : 0;
        s[threadIdx.x] = v;
        __syncthreads();
        for (int off = 1; off < SCAN_TPB; off <<= 1) {
            int t = (threadIdx.x >= off) ? s[threadIdx.x - off] : 0;
            __syncthreads();
            s[threadIdx.x] += t;
            __syncthreads();
        }
        int excl = s[threadIdx.x] - v;
        if (i < end) {
            rowptr[i] = carry + excl;
            int o = ocnt[i];
            ((float*)ocnt)[i] = rsqrtf((float)max(o, 1));
            ((float*)cnt)[i] = rsqrtf((float)max(v, 1));
        }
        int roundSum = s[SCAN_TPB - 1];
        __syncthreads();
        carry += roundSum;
    }
}

// ---------------- prep2: atomic-free CSR fill + x convert ----------------
// R16: fill position = rowptr[dst] (scattered L2 read, rowptr is 400KB cache-
// resident) + loc[e] (coalesced). No atomics left in this kernel.

__global__ void prep2(const int* __restrict__ src, const int* __restrict__ dst,
                      const int* __restrict__ loc, const int* __restrict__ rowptr,
                      int* __restrict__ eidx, int E,
                      const float* __restrict__ x, const float* __restrict__ invOut,
                      half_t* __restrict__ xh) {
    int t = blockIdx.x * blockDim.x + threadIdx.x;
    if (t < E) {
        eidx[rowptr[dst[t]] + loc[t]] = src[t];
    } else {
        int u = t - E;
        if (u < N_NODES * 32) {
            int n = u >> 5;
            float4 v = ((const float4*)x)[u];
            float s = invOut[n];
            v4h h;
            h[0] = (half_t)(v.x * s);
            h[1] = (half_t)(v.y * s);
            h[2] = (half_t)(v.z * s);
            h[3] = (half_t)(v.w * s);
            *(v4h*)(xh + (size_t)u * 4) = h;
        }
    }
}

// ---------------- CSR row segment-sum into fp32 acc[8] ----------------
// R11: idx prefetch one batch ahead (counted vmcnt, idx latency under accum).
// R13: dual-row interleave regressed — single row per thread is the keeper.
// R14/R15: gather lives in barrier-free, LDS-free kernels at 32 waves/CU.

template <int F>
__device__ __forceinline__ void gather_row(const half_t* __restrict__ x,
                                           const int* __restrict__ eidx,
                                           int beg, int end, int c, float* acc) {
    const half_t* __restrict__ xc = x + (size_t)c * 8;
    int n = end - beg;
    int nb = n & ~3;
    int j = 0;
    if (nb) {
        int i0 = eidx[beg + 0], i1 = eidx[beg + 1], i2 = eidx[beg + 2], i3 = eidx[beg + 3];
        do {
            v8h v0 = *(const v8h*)(xc + (size_t)i0 * F);
            v8h v1 = *(const v8h*)(xc + (size_t)i1 * F);
            v8h v2 = *(const v8h*)(xc + (size_t)i2 * F);
            v8h v3 = *(const v8h*)(xc + (size_t)i3 * F);
            j += 4;
            if (j < nb) {
                i0 = eidx[beg + j + 0];
                i1 = eidx[beg + j + 1];
                i2 = eidx[beg + j + 2];
                i3 = eidx[beg + j + 3];
            }
#pragma unroll
            for (int q = 0; q < 8; ++q)
                acc[q] += ((float)v0[q] + (float)v1[q]) + ((float)v2[q] + (float)v3[q]);
        } while (j < nb);
    }
    for (; j < n; ++j) {
        int s = eidx[beg + j];
        v8h val = *(const v8h*)(xc + (size_t)s * F);
#pragma unroll
        for (int q = 0; q < 8; ++q) acc[q] += (float)val[q];
    }
}

// ---------------- standalone gather kernels (no LDS, no barriers) --------

__global__ __launch_bounds__(256, 8) void gather1(
    const half_t* __restrict__ xh, const int* __restrict__ rowptr,
    const int* __restrict__ eidx, half_t* __restrict__ A1) {
    int t = blockIdx.x * 256 + threadIdx.x;
    int n = t >> 4, c = t & 15;
    if (n >= N_NODES) return;
    float acc[8] = {};
    gather_row<128>(xh, eidx, rowptr[n], rowptr[n + 1], c, acc);
    v8h o;
#pragma unroll
    for (int q = 0; q < 8; ++q) o[q] = (half_t)acc[q];
    *(v8h*)(A1 + (size_t)n * 128 + c * 8) = o;
}

// gather2: segsum(t2) with fused layer-2 epilogue:
//   A2 = relu((g*invIn + b2)*invOut) in fp16 (pre-scaled for layer-3 agg).
__global__ __launch_bounds__(256, 8) void gather2(
    const half_t* __restrict__ t2, const int* __restrict__ rowptr,
    const int* __restrict__ eidx, const float* __restrict__ invIn,
    const float* __restrict__ invOut, const float* __restrict__ b2,
    half_t* __restrict__ A2) {
    int t = blockIdx.x * 256 + threadIdx.x;
    int n = t >> 4, c = t & 15;
    if (n >= N_NODES) return;
    float acc[8] = {};
    gather_row<128>(t2, eidx, rowptr[n], rowptr[n + 1], c, acc);
    float ii = invIn[n], io = invOut[n];
    float4 blo = ((const float4*)b2)[c * 2];
    float4 bhi = ((const float4*)b2)[c * 2 + 1];
    float bb[8] = {blo.x, blo.y, blo.z, blo.w, bhi.x, bhi.y, bhi.z, bhi.w};
    v8h o;
#pragma unroll
    for (int q = 0; q < 8; ++q)
        o[q] = (half_t)fmaxf((acc[q] * ii + bb[q]) * io, 0.f);
    *(v8h*)(A2 + (size_t)n * 128 + c * 8) = o;
}

// ---------------- dense MLP kernels (uniform, MFMA-bound) ----------------
// mlp12: t2 = (relu((A1@W1)*invIn + b1)*invOut) @ W2.

__global__ __launch_bounds__(512) void mlp12(
    const half_t* __restrict__ A1, const half_t* __restrict__ Wt1,
    const half_t* __restrict__ Wt2,
    const float* __restrict__ invIn, const float* __restrict__ invOut,
    const float* __restrict__ b1, half_t* __restrict__ t2) {
    constexpr int K1 = 128, K2 = 256, N2 = 128;
    constexpr int LDA = K1 + 8;
    constexpr int LDH = K2 + 8;
    __shared__ half_t As[64][LDA];
    __shared__ half_t h1S[64][LDH];
    __shared__ float iiS[64], ioS[64];
    const int tid = threadIdx.x;
    const int wave = tid >> 6, lane = tid & 63;
    const int quad = lane >> 4, l16 = lane & 15;
    const int m0 = blockIdx.x * 64;
    const int n0 = wave * 32;   // GEMM1 column span per wave (8 waves x 32 = 256)

    // B1 fragments into registers (overlap with A-load)
    v8h b[2][4];
    float bv[2];
#pragma unroll
    for (int j = 0; j < 2; ++j) {
        int gn = n0 + j * 16 + l16;
        bv[j] = b1[gn];
#pragma unroll
        for (int kc = 0; kc < 4; ++kc)
            b[j][kc] = *(const v8h*)(Wt1 + (size_t)gn * K1 + kc * 32 + quad * 8);
    }
    if (tid < 64) {
        int gm = m0 + tid;
        bool ok = gm < N_NODES;
        iiS[tid] = ok ? invIn[gm] : 0.f;
        ioS[tid] = ok ? invOut[gm] : 0.f;
    }

    // A-tile load: 64 rows x 16 chunks = 1024 dwordx4, 2 per thread (coalesced)
#pragma unroll
    for (int p = 0; p < 2; ++p) {
        int task = tid + p * 512;
        int r = task >> 4, c = task & 15;
        int gm = m0 + r;
        v8h v = (gm < N_NODES) ? *(const v8h*)(A1 + (size_t)gm * K1 + c * 8)
                               : (v8h)(half_t)0;
        *(v8h*)&As[r][c * 8] = v;
    }
    __syncthreads();

    // GEMM1 -> h1S (LDS): 4 m-tiles x 2 n-tiles per wave
    for (int mt = 0; mt < 4; ++mt) {
        v8h a[4];
#pragma unroll
        for (int kc = 0; kc < 4; ++kc)
            a[kc] = *(const v8h*)&As[mt * 16 + l16][kc * 32 + quad * 8];
        v4f acc[2] = {};
#pragma unroll
        for (int kc = 0; kc < 4; ++kc)
#pragma unroll
            for (int j = 0; j < 2; ++j)
                acc[j] = __builtin_amdgcn_mfma_f32_16x16x32_f16(a[kc], b[j][kc], acc[j], 0, 0, 0);
#pragma unroll
        for (int j = 0; j < 2; ++j) {
            int cn = n0 + j * 16 + l16;
#pragma unroll
            for (int r = 0; r < 4; ++r) {
                int lr = mt * 16 + quad * 4 + r;
                float z = (acc[j][r] * iiS[lr] + bv[j]) * ioS[lr];
                h1S[lr][cn] = (half_t)fmaxf(z, 0.f);
            }
        }
    }

    // B2 fragments: 1 n-tile per wave (8 x 16 = 128 cols)
    v8h b2[8];
    const int n02 = wave * 16;
    {
        int gn = n02 + l16;
#pragma unroll
        for (int kc = 0; kc < 8; ++kc)
            b2[kc] = *(const v8h*)(Wt2 + (size_t)gn * K2 + kc * 32 + quad * 8);
    }
    __syncthreads();

    // GEMM2: t2 = h1S @ W2
    for (int mt = 0; mt < 4; ++mt) {
        v8h a2[8];
#pragma unroll
        for (int kc = 0; kc < 8; ++kc)
            a2[kc] = *(const v8h*)&h1S[mt * 16 + l16][kc * 32 + quad * 8];
        v4f acc2 = {};
#pragma unroll
        for (int kc = 0; kc < 8; ++kc)
            acc2 = __builtin_amdgcn_mfma_f32_16x16x32_f16(a2[kc], b2[kc], acc2, 0, 0, 0);
        int gn = n02 + l16;
#pragma unroll
        for (int r = 0; r < 4; ++r) {
            int gm = m0 + mt * 16 + quad * 4 + r;
            if (gm < N_NODES) t2[(size_t)gm * N2 + gn] = (half_t)acc2[r];
        }
    }
}

// mlp3: t3 = A2 @ W3 (A2 already relu'd + pre-scaled by gather2's epilogue).

__global__ __launch_bounds__(256) void mlp3(
    const half_t* __restrict__ A2, const half_t* __restrict__ Wt3,
    half_t* __restrict__ t3) {
    constexpr int K = 128, N = 40, LDA = K + 8;
    __shared__ half_t As[64][LDA];
    const int tid = threadIdx.x;
    const int wave = tid >> 6, lane = tid & 63;
    const int quad = lane >> 4, l16 = lane & 15;
    const int m0 = blockIdx.x * 64;

    v8h b[3][4];
#pragma unroll
    for (int j = 0; j < 3; ++j) {
        int gn = j * 16 + l16;
#pragma unroll
        for (int kc = 0; kc < 4; ++kc)
            b[j][kc] = (gn < N) ? *(const v8h*)(Wt3 + (size_t)gn * K + kc * 32 + quad * 8)
                                : (v8h)(half_t)0;
    }

#pragma unroll
    for (int p = 0; p < 4; ++p) {
        int task = tid + p * 256;
        int r = task >> 4, c = task & 15;
        int gm = m0 + r;
        v8h v = (gm < N_NODES) ? *(const v8h*)(A2 + (size_t)gm * K + c * 8)
                               : (v8h)(half_t)0;
        *(v8h*)&As[r][c * 8] = v;
    }
    __syncthreads();

    {
        int mt = wave;
        v8h a[4];
#pragma unroll
        for (int kc = 0; kc < 4; ++kc)
            a[kc] = *(const v8h*)&As[mt * 16 + l16][kc * 32 + quad * 8];
        v4f acc[3] = {};
#pragma unroll
        for (int kc = 0; kc < 4; ++kc)
#pragma unroll
            for (int j = 0; j < 3; ++j)
                acc[j] = __builtin_amdgcn_mfma_f32_16x16x32_f16(a[kc], b[j][kc], acc[j], 0, 0, 0);
#pragma unroll
        for (int j = 0; j < 3; ++j) {
            int gn = j * 16 + l16;
            if (gn >= N) continue;
#pragma unroll
            for (int r = 0; r < 4; ++r) {
                int gm = m0 + mt * 16 + quad * 4 + r;
                if (gm < N_NODES) t3[(size_t)gm * N + gn] = (half_t)acc[j][r];
            }
        }
    }
}

// ---------------- final gather (fp16 rows, fp32 out) ----------------

__global__ __launch_bounds__(256, 8) void gather_final(
    const half_t* __restrict__ x,
    const int* __restrict__ rowptr, const int* __restrict__ eidx,
    float* __restrict__ out, const float* __restrict__ invIn,
    const float* __restrict__ bias) {
    constexpr int F = 40, V = 5;
    int t = blockIdx.x * blockDim.x + threadIdx.x;
    int n = t / V;
    int v = t - n * V;
    if (n >= N_NODES) return;
    float acc[8] = {};
    gather_row<F>(x, eidx, rowptr[n], rowptr[n + 1], v, acc);
    float ii = invIn[n];
    float* o = out + (size_t)n * F + v * 8;
#pragma unroll
    for (int q = 0; q < 8; ++q) o[q] = acc[q] * ii + bias[v * 8 + q];
}

// ---------------- launch ----------------

extern "C" void kernel_launch(void* const* d_in, const int* in_sizes, int n_in,
                              void* d_out, int out_size, void* d_ws, size_t ws_size,
                              hipStream_t stream) {
    const float* x  = (const float*)d_in[0];
    const int* src  = (const int*)d_in[1];
    const int* dst  = (const int*)d_in[2];
    const float* W1 = (const float*)d_in[3];
    const float* b1 = (const float*)d_in[4];
    const float* W2 = (const float*)d_in[5];
    const float* b2 = (const float*)d_in[6];
    const float* W3 = (const float*)d_in[7];
    const float* b3 = (const float*)d_in[8];
    float* out = (float*)d_out;
    const int E = in_sizes[1];

    char* ws = (char*)d_ws;
    int* ocnt     = (int*)ws;                     // 100000 (becomes inv_out f32)
    int* icnt     = (int*)(ws + 400000);          // 100000 (becomes inv_in f32)
    int* rowptr   = (int*)(ws + 800000);          // 100001
    int* eidx     = (int*)(ws + 1600256);         // 800000 (3.2 MB)
    int* blockSum = (int*)(ws + 4800256);         // 128
    half_t* Wt1   = (half_t*)(ws + 4800768);      // 256x128 fp16 (64 KB)
    half_t* Wt2   = (half_t*)(ws + 4866304);      // 128x256 fp16 (64 KB)
    half_t* Wt3   = (half_t*)(ws + 4931840);      // 40x128 fp16 (10 KB)
    half_t* bufA  = (half_t*)(ws + 5000192);      // 25.6 MB: xh -> t2 -> t3
    half_t* bufB  = (half_t*)(ws + 30600192);     // 25.6 MB: loc -> A1 -> A2
    int* loc      = (int*)bufB;                   // 3.2 MB overlay, dead before gather1
    const float* inv_out = (const float*)ocnt;
    const float* inv_in  = (const float*)icnt;

    // ---- CSR + norms + weight conversion ----
    hipMemsetAsync(ocnt, 0, 800000, stream);
    prep1<<<(E + 70656 + 255) / 256, 256, 0, stream>>>(src, dst, ocnt, icnt, loc, E,
                                                       W1, W2, W3, Wt1, Wt2, Wt3);
    scan_reduce<<<SCAN_NB, SCAN_TPB, 0, stream>>>(icnt, blockSum, N_NODES);
    scan_offsets<<<1, SCAN_NB, 0, stream>>>(blockSum, rowptr + N_NODES);
    scan_final<<<SCAN_NB, SCAN_TPB, 0, stream>>>(icnt, ocnt, blockSum, rowptr, N_NODES);
    prep2<<<(E + N_NODES * 32 + 255) / 256, 256, 0, stream>>>(src, dst, loc, rowptr,
                                                              eidx, E, x, inv_out, bufA);

    const int NBG = (N_NODES * 16 + 255) / 256;  // 6250 (gather: 16 thr/row)
    const int NB  = (N_NODES + 63) / 64;         // 1563 (MLP: 64-row tiles)

    // Layer 1 aggregation: A1 = segsum(xh)          (reads bufA, writes bufB; loc dead)
    gather1<<<NBG, 256, 0, stream>>>(bufA, rowptr, eidx, bufB);
    // Layers 1+2 transform: t2 = MLP(A1)            (reads bufB, writes bufA; xh dead)
    mlp12<<<NB, 512, 0, stream>>>(bufB, Wt1, Wt2, inv_in, inv_out, b1, bufA);
    // Layer 2 aggregation + epilogue: A2            (reads bufA, writes bufB; A1 dead)
    gather2<<<NBG, 256, 0, stream>>>(bufA, rowptr, eidx, inv_in, inv_out, b2, bufB);
    // Layer 3 transform: t3 = A2 @ W3               (reads bufB, writes bufA; t2 dead)
    mlp3<<<NB, 256, 0, stream>>>(bufB, Wt3, bufA);
    // Final aggregation: out = segsum(t3)*inv_in+b3 (reads bufA)
    gather_final<<<(N_NODES * 5 + 255) / 256, 256, 0, stream>>>(
        bufA, rowptr, eidx, out, inv_in, b3);
}